// Round 7
// baseline (17.821 us; speedup 1.0000x reference)
//
#include <hip/hip_runtime.h>

// ContrastiveLoss collapses to:
//   v = sum_i mask_i * latent_i / max(||latent_i||, eps)   (64-vector)
//   out = COF1 * (||v||^2 - sum(mask)) / (2N)
// O(N*d), ~2 MB traffic -> launch/latency bound. Single fused dispatch,
// SPIN-FREE fan-in: every block release-publishes a MAGIC flag, then does a
// one-shot scan of all flags; whichever block sees the complete set (at
// minimum the temporally-last publisher) finalizes. Duplicate finalizers are
// benign (identical output); flags reset to 0 for the next graph replay;
// 0xAA poison != MAGIC so the first call is safe.

#define EPSV 1e-8f
#define COF1 0.01f

constexpr int N_ROWS = 8192;
constexpr int DIM = 64;
constexpr int TPB = 256;
constexpr int WPB = TPB / 64;                     // 4 waves/block
constexpr int BLOCKS = 128;                       // 512 waves (round-5 best)
constexpr int RPW = N_ROWS / (BLOCKS * WPB);      // 16 rows/wave
constexpr int SLOT = 68;                          // v[64] + cnt + pad
constexpr unsigned MAGIC = 0x5EEDF00Du;

__global__ __launch_bounds__(TPB, 2) void cl_fused(const float* __restrict__ latent,
                                                   float* __restrict__ ws,
                                                   unsigned* __restrict__ flags,
                                                   float* __restrict__ out) {
    const int wv   = threadIdx.x >> 6;
    const int lane = threadIdx.x & 63;
    const int g    = lane >> 4;      // row-group within a 4-row batch
    const int c4   = lane & 15;      // column quad (cols 4*c4..4*c4+3)
    const int row0 = (blockIdx.x * WPB + wv) * RPW;

    const float4* lat4 = (const float4*)latent;

    // ---- phase 1: per-wave partial (4 float4 batches staged up-front) ----
    float4 x[RPW / 4];
    #pragma unroll
    for (int b = 0; b < RPW / 4; ++b)
        x[b] = lat4[(row0 + b * 4 + g) * (DIM / 4) + c4];

    float4 v = make_float4(0.f, 0.f, 0.f, 0.f);
    float cnt = 0.0f;
    #pragma unroll
    for (int b = 0; b < RPW / 4; ++b) {
        float s = x[b].x + x[b].y + x[b].z + x[b].w;
        float q = x[b].x * x[b].x + x[b].y * x[b].y + x[b].z * x[b].z + x[b].w * x[b].w;
        #pragma unroll
        for (int off = 8; off; off >>= 1) {       // reduce within 16-lane row
            s += __shfl_xor(s, off);
            q += __shfl_xor(q, off);
        }
        if (s != 0.0f) {
            float inv = 1.0f / fmaxf(sqrtf(q), EPSV);
            v.x += x[b].x * inv; v.y += x[b].y * inv;
            v.z += x[b].z * inv; v.w += x[b].w * inv;
            if (c4 == 0) cnt += 1.0f;
        }
    }
    #pragma unroll
    for (int off = 16; off <= 32; off <<= 1) {    // combine 4 row-groups
        v.x += __shfl_xor(v.x, off); v.y += __shfl_xor(v.y, off);
        v.z += __shfl_xor(v.z, off); v.w += __shfl_xor(v.w, off);
        cnt += __shfl_xor(cnt, off);
    }

    __shared__ float4 sv4[WPB][16];
    __shared__ float  scnt[WPB];
    if (lane < 16) sv4[wv][c4] = v;
    if (lane == 0) scnt[wv] = cnt;
    __syncthreads();

    // ---- publish block partial + release flag ----
    if (wv == 0 && lane < 16) {
        float4 a = sv4[0][c4];
        float4 b1 = sv4[1][c4], b2 = sv4[2][c4], b3 = sv4[3][c4];
        a.x += b1.x + b2.x + b3.x; a.y += b1.y + b2.y + b3.y;
        a.z += b1.z + b2.z + b3.z; a.w += b1.w + b2.w + b3.w;
        ((float4*)(ws + blockIdx.x * SLOT))[c4] = a;
        if (lane == 0)
            ws[blockIdx.x * SLOT + 64] = scnt[0] + scnt[1] + scnt[2] + scnt[3];
        __threadfence();                           // writers fence their stores
    }
    __syncthreads();
    if (threadIdx.x == 0)
        __hip_atomic_store(&flags[blockIdx.x], MAGIC,
                           __ATOMIC_RELEASE, __HIP_MEMORY_SCOPE_AGENT);
    __syncthreads();   // own flag store durable before this block's scan

    // ---- one-shot scan (NO spin): am I the completing block? ----
    unsigned f = MAGIC;
    if (threadIdx.x < BLOCKS)
        f = __hip_atomic_load(&flags[threadIdx.x],
                              __ATOMIC_RELAXED, __HIP_MEMORY_SCOPE_AGENT);
    unsigned long long bal = __ballot(f == MAGIC);
    __shared__ unsigned wok[WPB];
    if (lane == 0) wok[wv] = (bal == ~0ull) ? 1u : 0u;
    __syncthreads();
    if (!(wok[0] & wok[1] & wok[2] & wok[3])) return;   // not complete -> exit

    __threadfence();                               // acquire: fresh slot reads

    // reset flags for the next replay (waves 1-2; idempotent across dups)
    if (threadIdx.x >= 64 && threadIdx.x < 64 + BLOCKS)
        flags[threadIdx.x - 64] = 0;

    if (wv != 0) return;

    // ---- single-wave final reduce over 128 slots ----
    const float4* ws4 = (const float4*)ws;         // 17 float4 per slot
    float4 vq = make_float4(0.f, 0.f, 0.f, 0.f);
    #pragma unroll
    for (int j = 0; j < 32; ++j) {                 // slot s = 4*j + g, quad c4
        float4 t = ws4[(4 * j + g) * (SLOT / 4) + c4];
        vq.x += t.x; vq.y += t.y; vq.z += t.z; vq.w += t.w;
    }
    float c = ws[lane * SLOT + 64] + ws[(64 + lane) * SLOT + 64];

    #pragma unroll
    for (int off = 16; off <= 32; off <<= 1) {     // combine slot-groups
        vq.x += __shfl_xor(vq.x, off); vq.y += __shfl_xor(vq.y, off);
        vq.z += __shfl_xor(vq.z, off); vq.w += __shfl_xor(vq.w, off);
    }
    #pragma unroll
    for (int off = 32; off; off >>= 1)             // total count
        c += __shfl_xor(c, off);

    float d = vq.x * vq.x + vq.y * vq.y + vq.z * vq.z + vq.w * vq.w;
    #pragma unroll
    for (int off = 8; off; off >>= 1)              // sum 16 distinct c4
        d += __shfl_xor(d, off);

    if (lane == 0)
        out[0] = COF1 * (d - c) / (2.0f * (float)N_ROWS);
}

extern "C" void kernel_launch(void* const* d_in, const int* in_sizes, int n_in,
                              void* d_out, int out_size, void* d_ws, size_t ws_size,
                              hipStream_t stream) {
    const float* latent = (const float*)d_in[0];
    float* out = (float*)d_out;
    float* ws = (float*)d_ws;                          // 128*68*4 = 34,816 B
    unsigned* flags = (unsigned*)(ws + BLOCKS * SLOT); // +512 B

    cl_fused<<<BLOCKS, TPB, 0, stream>>>(latent, ws, flags, out);
}

// Round 8
// 11.676 us; speedup vs baseline: 1.5262x; 1.5262x over previous
//
#include <hip/hip_runtime.h>

// ContrastiveLoss collapses to:
//   v = sum_i mask_i * latent_i / max(||latent_i||, eps)   (64-vector)
//   out = COF1 * (||v||^2 - sum(mask)) / (2N)
// O(N*d), ~2 MB traffic -> launch/latency bound.
// Settled structure: TWO dispatches. Both fused single-dispatch designs
// (spin fan-in r4: 18.0us; one-shot scan r7: 17.8us + a 30ms straggler)
// lost to a 2nd graph node (~3us) because device-scope fences/flag traffic
// cross non-coherent XCD L2s. This round: r5's best partial (128 blocks)
// + r7's single-wave one-round-trip final.

#define EPSV 1e-8f
#define COF1 0.01f

constexpr int N_ROWS = 8192;
constexpr int DIM = 64;
constexpr int TPB = 256;
constexpr int WPB = TPB / 64;                     // 4 waves/block
constexpr int BLOCKS = 128;                       // 512 waves (r5 best)
constexpr int RPW = N_ROWS / (BLOCKS * WPB);      // 16 rows/wave
constexpr int SLOT = 68;                          // v[64] + cnt + pad (16B align)

// Kernel 1: lane L -> row-group g=L>>4, column quad c4=L&15. All 4 float4
// batches issued up-front (one memory round trip); independent shuffle
// chains overlap. Block combines 4 waves in LDS -> one 68-float slot.
__global__ __launch_bounds__(TPB, 2) void cl_partial(const float* __restrict__ latent,
                                                     float* __restrict__ ws) {
    const int wv   = threadIdx.x >> 6;
    const int lane = threadIdx.x & 63;
    const int g    = lane >> 4;
    const int c4   = lane & 15;
    const int row0 = (blockIdx.x * WPB + wv) * RPW;

    const float4* lat4 = (const float4*)latent;

    float4 x[RPW / 4];
    #pragma unroll
    for (int b = 0; b < RPW / 4; ++b)
        x[b] = lat4[(row0 + b * 4 + g) * (DIM / 4) + c4];

    float4 v = make_float4(0.f, 0.f, 0.f, 0.f);
    float cnt = 0.0f;
    #pragma unroll
    for (int b = 0; b < RPW / 4; ++b) {
        float s = x[b].x + x[b].y + x[b].z + x[b].w;
        float q = x[b].x * x[b].x + x[b].y * x[b].y + x[b].z * x[b].z + x[b].w * x[b].w;
        #pragma unroll
        for (int off = 8; off; off >>= 1) {       // reduce within 16-lane row group
            s += __shfl_xor(s, off);
            q += __shfl_xor(q, off);
        }
        if (s != 0.0f) {
            float inv = 1.0f / fmaxf(sqrtf(q), EPSV);
            v.x += x[b].x * inv; v.y += x[b].y * inv;
            v.z += x[b].z * inv; v.w += x[b].w * inv;
            if (c4 == 0) cnt += 1.0f;             // one count per row
        }
    }
    #pragma unroll
    for (int off = 16; off <= 32; off <<= 1) {    // combine the 4 row-groups
        v.x += __shfl_xor(v.x, off); v.y += __shfl_xor(v.y, off);
        v.z += __shfl_xor(v.z, off); v.w += __shfl_xor(v.w, off);
        cnt += __shfl_xor(cnt, off);
    }

    __shared__ float4 sv4[WPB][16];
    __shared__ float  scnt[WPB];
    if (lane < 16) sv4[wv][c4] = v;
    if (lane == 0) scnt[wv] = cnt;
    __syncthreads();

    if (wv == 0 && lane < 16) {
        float4 a = sv4[0][c4];
        float4 b1 = sv4[1][c4], b2 = sv4[2][c4], b3 = sv4[3][c4];
        a.x += b1.x + b2.x + b3.x; a.y += b1.y + b2.y + b3.y;
        a.z += b1.z + b2.z + b3.z; a.w += b1.w + b2.w + b3.w;
        ((float4*)(ws + blockIdx.x * SLOT))[c4] = a;
        if (lane == 0)
            ws[blockIdx.x * SLOT + 64] = scnt[0] + scnt[1] + scnt[2] + scnt[3];
    }
}

// Kernel 2: ONE wave, one round trip. 32 float4 loads/lane cover all
// 128 slots x 64 components (slot s = 4*j + g, quad c4); counts via two
// scalar loads/lane. Cross-lane combine, finalize. No LDS, no sync.
__global__ __launch_bounds__(64) void cl_final(const float* __restrict__ ws,
                                               float* __restrict__ out) {
    const int lane = threadIdx.x;                  // 64 threads = 1 wave
    const int g    = lane >> 4;
    const int c4   = lane & 15;
    const float4* ws4 = (const float4*)ws;         // 17 float4 per slot

    float4 vq = make_float4(0.f, 0.f, 0.f, 0.f);
    #pragma unroll
    for (int j = 0; j < 32; ++j) {                 // slot s = 4*j + g
        float4 t = ws4[(4 * j + g) * (SLOT / 4) + c4];
        vq.x += t.x; vq.y += t.y; vq.z += t.z; vq.w += t.w;
    }
    float c = ws[lane * SLOT + 64] + ws[(64 + lane) * SLOT + 64];

    #pragma unroll
    for (int off = 16; off <= 32; off <<= 1) {     // combine slot-groups
        vq.x += __shfl_xor(vq.x, off); vq.y += __shfl_xor(vq.y, off);
        vq.z += __shfl_xor(vq.z, off); vq.w += __shfl_xor(vq.w, off);
    }
    #pragma unroll
    for (int off = 32; off; off >>= 1)             // total count
        c += __shfl_xor(c, off);

    float d = vq.x * vq.x + vq.y * vq.y + vq.z * vq.z + vq.w * vq.w;
    #pragma unroll
    for (int off = 8; off; off >>= 1)              // sum the 16 distinct c4
        d += __shfl_xor(d, off);

    if (lane == 0)
        out[0] = COF1 * (d - c) / (2.0f * (float)N_ROWS);
}

extern "C" void kernel_launch(void* const* d_in, const int* in_sizes, int n_in,
                              void* d_out, int out_size, void* d_ws, size_t ws_size,
                              hipStream_t stream) {
    const float* latent = (const float*)d_in[0];
    float* out = (float*)d_out;
    float* ws = (float*)d_ws;   // 128*68*4 = 34,816 bytes

    cl_partial<<<BLOCKS, TPB, 0, stream>>>(latent, ws);
    cl_final<<<1, 64, 0, stream>>>(ws, out);
}